// Round 15
// baseline (1342.660 us; speedup 1.0000x reference)
//
#include <hip/hip_runtime.h>
#include <hip/hip_bf16.h>

#define DIMD 256
#define DIMC 64
#define WTS  264   // wt k-stride (bf16): 528B rows, 16B-aligned, bank-spread

typedef __attribute__((ext_vector_type(8))) __bf16 bf16x8;
typedef __attribute__((ext_vector_type(4))) float f32x4;

__global__ __launch_bounds__(256, 2) void tree_node_kernel(
    const float* __restrict__ x,
    const float* __restrict__ w_router,
    const float* __restrict__ b_router,
    const float* __restrict__ w_left,
    const float* __restrict__ b_left,
    const float* __restrict__ w_right,
    const float* __restrict__ b_right,
    float* __restrict__ out,
    int tpw)                         // tiles per wave
{
    __shared__ __bf16 wt[128 * WTS];    // [col: L=0-63, R=64-127][k]  67.6 KB
    __shared__ float  wr_s[DIMD];       // router weights
    __shared__ float  bb_s[2 * DIMC];   // biases L|R

    const int tid  = threadIdx.x;
    const int lane = tid & 63;
    const int wave = tid >> 6;
    const int g    = lane >> 4;         // k-group 0..3
    const int m    = lane & 15;         // token within tile

    // each WAVE is an independent stream: dense front over global wave id
    const int wid = blockIdx.x * 4 + wave;
    const int NW  = gridDim.x * 4;
    size_t row0 = (size_t)wid * 16;
    const size_t rstep = (size_t)NW * 16;

    // 4-slot rolling ring of x slices: slot s&3 holds this lane's 32B k-slice
    // for step s. Per instruction the wave covers 16 rows x 128B (full lines).
    f32x4 px[4][2];
#define ISSUE(slot, rowbase, s_)                                              \
    {                                                                         \
        const float* p_ = x + ((rowbase) + m) * DIMD + (s_) * 32 + g * 8;     \
        px[slot][0] = *(const f32x4*)p_;                                      \
        px[slot][1] = *(const f32x4*)(p_ + 4);                                \
    }

    // prefill tile 0 steps 0..3 -- these loads fly during weight staging
    ISSUE(0, row0, 0) ISSUE(1, row0, 1) ISSUE(2, row0, 2) ISSUE(3, row0, 3)

    // ---- stage weights transposed to LDS (once): wt[c][k] = w[k][c] ----
    for (int idx = tid; idx < DIMD * DIMC; idx += 256) {
        const int k = idx >> 6, c = idx & 63;
        wt[c * WTS + k]          = (__bf16)w_left[idx];
        wt[(64 + c) * WTS + k]   = (__bf16)w_right[idx];
    }
    if (tid < DIMD) wr_s[tid] = w_router[tid];
    if (tid < DIMC) { bb_s[tid] = b_left[tid]; bb_s[DIMC + tid] = b_right[tid]; }
    const float brout = b_router[0];
    __syncthreads();   // the ONLY barrier; waves free-run after this

    // hoisted per-lane biases (this lane's 4 cols per col-tile)
    f32x4 bL4[4], bR4[4];
#pragma unroll
    for (int ct = 0; ct < 4; ++ct) {
        bL4[ct] = *(const f32x4*)&bb_s[ct * 16 + g * 4];
        bR4[ct] = *(const f32x4*)&bb_s[DIMC + ct * 16 + g * 4];
    }

    // one K-step: consume slot, fold fp64 router, reissue slot, 8 MFMA
    // (4 col-tiles x 2 children; w A-frags from LDS, conflict-free b128)
#define STEP(s_, rnext_, snext_, cond_)                                       \
    {                                                                         \
        const f32x4 lo = px[(s_) & 3][0], hi = px[(s_) & 3][1];               \
        const f32x4 wlo = *(const f32x4*)&wr_s[(s_) * 32 + g * 8];            \
        const f32x4 whi = *(const f32x4*)&wr_s[(s_) * 32 + g * 8 + 4];        \
        bf16x8 a;                                                             \
        _Pragma("unroll")                                                     \
        for (int j = 0; j < 4; ++j) {                                         \
            a[j]     = (__bf16)lo[j];                                         \
            a[j + 4] = (__bf16)hi[j];                                         \
            racc += (double)lo[j] * (double)wlo[j]                            \
                  + (double)hi[j] * (double)whi[j];                           \
        }                                                                     \
        if (cond_) ISSUE((s_) & 3, rnext_, snext_)                            \
        _Pragma("unroll")                                                     \
        for (int ct = 0; ct < 4; ++ct) {                                      \
            const bf16x8 wfL = *(const bf16x8*)                               \
                &wt[(ct * 16 + m) * WTS + (s_) * 32 + g * 8];                 \
            const bf16x8 wfR = *(const bf16x8*)                               \
                &wt[(64 + ct * 16 + m) * WTS + (s_) * 32 + g * 8];            \
            accL[ct] = __builtin_amdgcn_mfma_f32_16x16x32_bf16(wfL, a, accL[ct], 0, 0, 0); \
            accR[ct] = __builtin_amdgcn_mfma_f32_16x16x32_bf16(wfR, a, accR[ct], 0, 0, 0); \
        }                                                                     \
    }

    for (int j = 0; j < tpw; ++j) {
        const size_t rnext = row0 + rstep;
        const bool   more  = (j + 1 < tpw);
        double racc = 0.0;
        f32x4 accL[4], accR[4];
#pragma unroll
        for (int ct = 0; ct < 4; ++ct) {
            accL[ct] = (f32x4){0.f, 0.f, 0.f, 0.f};
            accR[ct] = (f32x4){0.f, 0.f, 0.f, 0.f};
        }

        STEP(0, row0,  4, true)    // consume (j,0), issue (j,4)
        STEP(1, row0,  5, true)
        STEP(2, row0,  6, true)
        STEP(3, row0,  7, true)
        STEP(4, rnext, 0, more)    // consume (j,4), issue (j+1,0)
        STEP(5, rnext, 1, more)
        STEP(6, rnext, 2, more)
        STEP(7, rnext, 3, more)

        // router: reduce fp64 partials over the 4 g-lanes of token m
        racc += __shfl_xor(racc, 16);
        racc += __shfl_xor(racc, 32);
        const bool lsel = ((float)(racc + (double)brout) > 0.0f);

        // epilogue: select + bias, 4 x 16B direct stores (v11-verified layout:
        // acc[ct][r] = out[token m][col ct*16 + g*4 + r])
        float* orow = out + (row0 + m) * DIMC;
#pragma unroll
        for (int ct = 0; ct < 4; ++ct) {
            f32x4 ov;
#pragma unroll
            for (int r = 0; r < 4; ++r)
                ov[r] = lsel ? (accL[ct][r] + bL4[ct][r])
                             : (accR[ct][r] + bR4[ct][r]);
            *(f32x4*)(orow + ct * 16 + g * 4) = ov;
        }

        row0 = rnext;
    }
#undef ISSUE
#undef STEP
}

extern "C" void kernel_launch(void* const* d_in, const int* in_sizes, int n_in,
                              void* d_out, int out_size, void* d_ws, size_t ws_size,
                              hipStream_t stream) {
    const float* x        = (const float*)d_in[0];
    const float* w_router = (const float*)d_in[1];
    const float* b_router = (const float*)d_in[2];
    const float* w_left   = (const float*)d_in[3];
    const float* b_left   = (const float*)d_in[4];
    const float* w_right  = (const float*)d_in[5];
    const float* b_right  = (const float*)d_in[6];
    float* out = (float*)d_out;

    const int n_tok = in_sizes[0] / DIMD;        // 1,048,576
    const int grid  = 512;                       // 2 blocks/CU (LDS ~69 KB)
    const int tpw   = n_tok / (grid * 4 * 16);   // 32 tiles per wave

    tree_node_kernel<<<grid, 256, 0, stream>>>(
        x, w_router, b_router, w_left, b_left, w_right, b_right, out, tpw);
}